// Round 14
// baseline (117.521 us; speedup 1.0000x reference)
//
#include <hip/hip_runtime.h>
#include <hip/hip_bf16.h>
#include <math.h>

// Problem constants: B=4, Q=100, T=20, H=W=128 (HW=16384), C=80
#define B_ 4
#define Q_ 100
#define T_ 20
#define C_ 80
#define HW_ 16384
#define HW4_ (HW_ / 4)

#define QH_ 64                   // queries per block (lane = query)
#define NQH_ 2                   // 2 query-halves (q0..63, q64..99 + 28 dead lanes)
#define PB_ 256                  // pixels per block
#define NCH_ (HW_ / PB_)         // 64 pixel-chunks
#define PT_ 64                   // pixels per tile (16 f4 granules)
#define NT_ (PB_ / PT_)          // 4 tiles per block
#define NV_ 41                   // values per lane: 20 L + 20 I + osum

// smem partition (floats): o tiles rotated-[64q][16 f4], g tiles [64p][24]
#define LO_SZ 4096               // per buffer
#define LG_SZ 1536               // per buffer
#define SMEM_FLOATS (2 * LO_SZ + 2 * LG_SZ)   // 11264 floats = 45056 B
// epilogue reduce area needs 4*64*41 = 10496 floats <= 11264: reuse smem

// workspace: WS[(b*2+qh)*NCH + ch][NV_][64q]  then tsum[B*T]
#define WS_CELLS (B_ * NQH_ * NCH_)           // 512
#define TS_OFF ((size_t)WS_CELLS * NV_ * 64)  // 1343488

typedef float f32x4 __attribute__((ext_vector_type(4)));

// ---------- Kernel 0: tsum[b*T+t] = sum of target mask ----------
__global__ __launch_bounds__(256) void gsum_kernel(const float* __restrict__ tgt,
                                                   float* __restrict__ ws) {
    const int bt = blockIdx.x;
    const f32x4* p = (const f32x4*)(tgt + (size_t)bt * HW_);
    float s = 0.f;
    for (int i = threadIdx.x; i < HW4_ / 4; i += 256) {   // HW_/4 = 4096 f4
        f32x4 v = p[i];
        s += (v.x + v.y) + (v.z + v.w);
    }
    s += __shfl_down(s, 32); s += __shfl_down(s, 16); s += __shfl_down(s, 8);
    s += __shfl_down(s, 4);  s += __shfl_down(s, 2);  s += __shfl_down(s, 1);
    __shared__ float red[4];
    if ((threadIdx.x & 63) == 0) red[threadIdx.x >> 6] = s;
    __syncthreads();
    if (threadIdx.x == 0) ws[TS_OFF + bt] = red[0] + red[1] + red[2] + red[3];
}

// ---------- Kernel 1: lane=query transposed main kernel ----------
__global__ __launch_bounds__(256) void partial_kernel(const float* __restrict__ outm,
                                                      const float* __restrict__ tgtm,
                                                      float* __restrict__ ws) {
    __shared__ __align__(16) float smem[SMEM_FLOATS];

    const int bid = blockIdx.x;          // [0,512): (b, qh, ch)
    const int b   = bid >> 7;
    const int qh  = (bid >> 6) & 1;
    const int ch  = bid & 63;

    const int tid  = threadIdx.x;
    const int lane = tid & 63;
    const int w    = tid >> 6;

    const float* obase = outm + ((size_t)b * Q_ + qh * QH_) * HW_;
    const float* gbase = tgtm + (size_t)b * T_ * HW_;
    const int pixf4 = ch * (PB_ / 4);    // block's pixel base in f4 units

    // staging maps
    const int srow = tid >> 2;                   // o row (query) 0..63
    const int sc4b = (tid & 3) * 4;              // 4 f4 per thread
    const bool qok = (qh * QH_ + srow) < Q_;
    const f32x4* of4 = (const f32x4*)obase + (size_t)srow * HW4_ + pixf4;
    const int gt0 = tid >> 4, gc0 = tid & 15;    // g f4 idx = tid       (t 0..15)
    const int gt1 = 16 + (tid >> 4), gc1 = tid & 15;  // idx 256+tid (t 16..19, tid<64)

    f32x4 so[4], sg0, sg1;
    f32x4 zf4; zf4.x = zf4.y = zf4.z = zf4.w = 0.f;

    auto LOAD = [&](int tile) {
        const int tf = tile * 16;
#pragma unroll
        for (int k = 0; k < 4; ++k)
            so[k] = qok ? of4[tf + sc4b + k] : zf4;
        sg0 = ((const f32x4*)gbase)[(size_t)gt0 * HW4_ + pixf4 + tf + gc0];
        if (tid < 64)
            sg1 = ((const f32x4*)gbase)[(size_t)gt1 * HW4_ + pixf4 + tf + gc1];
    };
    auto WRITE = [&](int buf) {
        float* lo = smem + buf * LO_SZ;
        float* lg = smem + 2 * LO_SZ + buf * LG_SZ;
#pragma unroll
        for (int k = 0; k < 4; ++k) {
            const int gr = (sc4b + k + srow) & 15;       // f4-rotation by row
            *(f32x4*)(lo + srow * 64 + gr * 4) = so[k];  // 16B-aligned
        }
#pragma unroll
        for (int j = 0; j < 4; ++j) lg[(gc0 * 4 + j) * 24 + gt0] = sg0[j];
        if (tid < 64) {
#pragma unroll
            for (int j = 0; j < 4; ++j) lg[(gc1 * 4 + j) * 24 + gt1] = sg1[j];
        }
    };

    float accL[T_], accI[T_], osum = 0.f;
#pragma unroll
    for (int t = 0; t < T_; ++t) { accL[t] = 0.f; accI[t] = 0.f; }

    auto COMPUTE = [&](int buf) {
        const float* lo = smem + buf * LO_SZ;
        const float* lg = smem + 2 * LO_SZ + buf * LG_SZ;
#pragma unroll
        for (int mm = 0; mm < 4; ++mm) {
            const int m  = w * 4 + mm;                  // granule (4 pixels) in tile
            const int gr = (m + lane) & 15;
            const f32x4 ov = *(const f32x4*)(lo + lane * 64 + gr * 4);
#pragma unroll
            for (int j = 0; j < 4; ++j) {
                const int p = m * 4 + j;
                const float o = ov[j];
                osum += o;
#pragma unroll
                for (int tg = 0; tg < 5; ++tg) {
                    const f32x4 gv = *(const f32x4*)(lg + p * 24 + tg * 4);
#pragma unroll
                    for (int jj = 0; jj < 4; ++jj) {
                        accL[tg * 4 + jj] += fabsf(o - gv[jj]);
                        accI[tg * 4 + jj] = fmaf(o, gv[jj], accI[tg * 4 + jj]);
                    }
                }
            }
        }
    };

    // Pipeline: issue loads early, write late (T14), one barrier per tile.
    LOAD(0); WRITE(0); __syncthreads();
#pragma unroll
    for (int tile = 0; tile < NT_; ++tile) {
        if (tile + 1 < NT_) LOAD(tile + 1);
        COMPUTE(tile & 1);
        if (tile + 1 < NT_) WRITE((tile + 1) & 1);
        __syncthreads();
    }

    // Epilogue: per-wave per-lane 41 values -> smem, cross-wave sum, store.
    {
        float* rl = smem + (size_t)(w * 64 + lane) * NV_;
#pragma unroll
        for (int t = 0; t < T_; ++t) { rl[t] = accL[t]; rl[T_ + t] = accI[t]; }
        rl[40] = osum;
    }
    __syncthreads();
    {
        const int l  = tid & 63;
        const int vg = tid >> 6;
        const int vstart = (vg == 0) ? 0 : (11 + (vg - 1) * 10);
        const int vcnt   = (vg == 0) ? 11 : 10;
        float* wout = ws + (size_t)bid * NV_ * 64;
        for (int v = vstart; v < vstart + vcnt; ++v) {
            const float s = smem[(0 * 64 + l) * NV_ + v] + smem[(1 * 64 + l) * NV_ + v] +
                            smem[(2 * 64 + l) * NV_ + v] + smem[(3 * 64 + l) * NV_ + v];
            wout[(size_t)v * 64 + l] = s;
        }
    }
}

// ---------- Kernel 2: sum chunks + softmax/dice epilogue ----------
__global__ __launch_bounds__(64) void finalize_kernel(const float* __restrict__ probs,
                                                      const int*   __restrict__ labels,
                                                      const float* __restrict__ ws,
                                                      float* __restrict__ out) {
    const int bq = blockIdx.x;
    const int b = bq / Q_;
    const int q = bq % Q_;
    const int qh = q >> 6;
    const int l  = q & 63;

    __shared__ float s_logit[C_];
    for (int c = threadIdx.x; c < C_; c += 64)
        s_logit[c] = probs[(size_t)bq * C_ + c];
    __syncthreads();

    const int t = threadIdx.x;
    if (t < T_) {
        const float* base = ws + ((size_t)(b * NQH_ + qh) * NCH_) * NV_ * 64;
        float L = 0.f, I = 0.f, osum = 0.f;
        for (int c = 0; c < NCH_; ++c) {
            const float* cell = base + (size_t)c * NV_ * 64;
            L    += cell[(size_t)t * 64 + l];
            I    += cell[(size_t)(T_ + t) * 64 + l];
            osum += cell[(size_t)40 * 64 + l];
        }
        const float tsum = ws[TS_OFF + (size_t)b * T_ + t];

        float mx = -INFINITY;
#pragma unroll
        for (int c = 0; c < C_; ++c) mx = fmaxf(mx, s_logit[c]);
        float sum = 0.f;
#pragma unroll
        for (int c = 0; c < C_; ++c) sum += __expf(s_logit[c] - mx);
        const int lab = labels[(size_t)b * T_ + t];
        const float p = __expf(s_logit[lab] - mx) / sum;

        const float denom = osum + tsum;
        const float dice = 1.f - (2.f * I + 1.f) / (denom + 1.f);

        out[(size_t)bq * T_ + t] = L - p + dice;
    }
}

extern "C" void kernel_launch(void* const* d_in, const int* in_sizes, int n_in,
                              void* d_out, int out_size, void* d_ws, size_t ws_size,
                              hipStream_t stream) {
    const float* out_probs     = (const float*)d_in[0]; // [B,Q,C]
    const float* out_masks     = (const float*)d_in[1]; // [B,Q,H,W]
    const float* target_masks  = (const float*)d_in[2]; // [B,T,H,W]
    const int*   target_labels = (const int*)d_in[3];   // [B,T]
    float* out = (float*)d_out;                         // [B,Q,T]

    float* partials = (float*)d_ws;                     // ~5.4 MB

    gsum_kernel<<<B_ * T_, 256, 0, stream>>>(target_masks, partials);
    partial_kernel<<<B_ * NQH_ * NCH_, 256, 0, stream>>>(out_masks, target_masks, partials);
    finalize_kernel<<<B_ * Q_, 64, 0, stream>>>(out_probs, target_labels, partials, out);
}

// Round 15
// 44.400 us; speedup vs baseline: 2.6469x; 2.6469x over previous
//
#include <hip/hip_runtime.h>
#include <hip/hip_bf16.h>
#include <math.h>

// Problem constants: B=4, Q=100, T=20, H=W=128 (HW=16384), C=80
#define B_ 4
#define Q_ 100
#define T_ 20
#define C_ 80
#define HW_ 16384
#define HW4_ (HW_ / 4)

#define S_ 16                    // segments over HW
#define QG_ 5                    // queries per block (shared by all 4 waves via L1)
#define NQG_ (Q_ / QG_)          // 20 query-groups
#define TW_ 5                    // targets per wave (4 waves = 4 t-strips)
#define SEG4_ (HW_ / S_ / 4)     // 256 float4 per segment
#define NIT_ (SEG4_ / 64)        // 4 iterations per wave
#define NWG_ (B_ * NQG_ * S_)    // 1280 blocks

// Workspace float offsets (sub-partial layout: [..][S_][4])
#define WL_OFF 0                                   // [B*Q][T][S_][4] = 512000
#define WI_OFF (B_ * Q_ * T_ * S_ * 4)             // 512000
#define OS_OFF (2 * B_ * Q_ * T_ * S_ * 4)         // 1024000: [B*Q][S_][4]
#define GS_OFF (OS_OFF + B_ * Q_ * S_ * 4)         // 1049600: [B*T][S_][4]

typedef float f32x4 __attribute__((ext_vector_type(4)));

__device__ __forceinline__ f32x4 ldnt(const f32x4* p) {
    return __builtin_nontemporal_load(p);   // o is stream-once: keep L2 for g
}

// 4-stage reduce: lanes 0..3 hold disjoint 16-lane partials (sum = wave sum).
__device__ __forceinline__ float wred4(float v) {
    v += __shfl_down(v, 32);
    v += __shfl_down(v, 16);
    v += __shfl_down(v, 8);
    v += __shfl_down(v, 4);
    return v;
}

// One wave per (b, q-group, t-strip, seg): 5x5 register tile, no LDS, no barriers.
template <bool WITH_G>
__device__ __forceinline__ void partial_body(const f32x4* __restrict__ o4,  // +seg+lane
                                             const f32x4* __restrict__ g4,  // +seg+lane
                                             float* __restrict__ ws,
                                             int qglob,    // first global q of group
                                             int b, int seg, int lane, int ts) {
    const int t0 = ts * TW_;

    float accL[QG_][TW_], accI[QG_][TW_], os[QG_], gs[TW_];
#pragma unroll
    for (int qi = 0; qi < QG_; ++qi) {
        os[qi] = 0.f;
#pragma unroll
        for (int tj = 0; tj < TW_; ++tj) { accL[qi][tj] = 0.f; accI[qi][tj] = 0.f; }
    }
#pragma unroll
    for (int tj = 0; tj < TW_; ++tj) gs[tj] = 0.f;

#pragma unroll
    for (int it = 0; it < NIT_; ++it) {
        const int ofs = it * 64;
        f32x4 o[QG_];
#pragma unroll
        for (int qi = 0; qi < QG_; ++qi) o[qi] = ldnt(o4 + (size_t)qi * HW4_ + ofs);
        f32x4 g[TW_];
#pragma unroll
        for (int tj = 0; tj < TW_; ++tj) g[tj] = g4[(size_t)(t0 + tj) * HW4_ + ofs];

        if (ts == 0) {   // wave-uniform: osum by one t-strip only
#pragma unroll
            for (int qi = 0; qi < QG_; ++qi)
                os[qi] += (o[qi].x + o[qi].y) + (o[qi].z + o[qi].w);
        }
        if (WITH_G) {    // gsum by q-group 0 blocks only
#pragma unroll
            for (int tj = 0; tj < TW_; ++tj)
                gs[tj] += (g[tj].x + g[tj].y) + (g[tj].z + g[tj].w);
        }
#pragma unroll
        for (int tj = 0; tj < TW_; ++tj) {
#pragma unroll
            for (int qi = 0; qi < QG_; ++qi) {
                accL[qi][tj] += (fabsf(o[qi].x - g[tj].x) + fabsf(o[qi].y - g[tj].y)) +
                                (fabsf(o[qi].z - g[tj].z) + fabsf(o[qi].w - g[tj].w));
                accI[qi][tj] = fmaf(o[qi].x, g[tj].x, accI[qi][tj]);
                accI[qi][tj] = fmaf(o[qi].y, g[tj].y, accI[qi][tj]);
                accI[qi][tj] = fmaf(o[qi].z, g[tj].z, accI[qi][tj]);
                accI[qi][tj] = fmaf(o[qi].w, g[tj].w, accI[qi][tj]);
            }
        }
    }

    // Epilogue: 4-stage reduces; lanes 0..3 write sub-partials.
    float* WL = ws + WL_OFF;
    float* WI = ws + WI_OFF;
    float* OS = ws + OS_OFF;
    float* GS = ws + GS_OFF;
#pragma unroll
    for (int qi = 0; qi < QG_; ++qi) {
#pragma unroll
        for (int tj = 0; tj < TW_; ++tj) {
            const float vL = wred4(accL[qi][tj]);
            const float vI = wred4(accI[qi][tj]);
            if (lane < 4) {
                const size_t idx = ((size_t)(qglob + qi) * T_ + t0 + tj) * (S_ * 4)
                                   + seg * 4 + lane;
                WL[idx] = vL;
                WI[idx] = vI;
            }
        }
        if (ts == 0) {
            const float vo = wred4(os[qi]);
            if (lane < 4) OS[(size_t)(qglob + qi) * (S_ * 4) + seg * 4 + lane] = vo;
        }
    }
    if (WITH_G) {
#pragma unroll
        for (int tj = 0; tj < TW_; ++tj) {
            const float vg = wred4(gs[tj]);
            if (lane < 4) GS[(size_t)(b * T_ + t0 + tj) * (S_ * 4) + seg * 4 + lane] = vg;
        }
    }
}

__global__ __launch_bounds__(256) void partial_kernel(const float* __restrict__ outm,
                                                      const float* __restrict__ tgtm,
                                                      float* __restrict__ ws) {
    // XCD-batch partition: batch b on XCD pair {2b,2b+1} (320 blocks per batch).
    const int r = blockIdx.x & 7;
    const int m = blockIdx.x >> 3;
    const int b = r >> 1;
    const int l = m * 2 + (r & 1);   // [0,320): qg(20) x seg(16)
    const int qg = l >> 4;
    const int seg = l & (S_ - 1);
    const int qglob = b * Q_ + qg * QG_;

    const int lane = threadIdx.x & 63;
    const int ts   = threadIdx.x >> 6;   // t-strip = wave id

    const f32x4* o4 = (const f32x4*)(outm + (size_t)qglob * HW_) + seg * SEG4_ + lane;
    const f32x4* g4 = (const f32x4*)(tgtm + (size_t)b * T_ * HW_) + seg * SEG4_ + lane;

    if (qg == 0) partial_body<true>(o4, g4, ws, qglob, b, seg, lane, ts);
    else         partial_body<false>(o4, g4, ws, qglob, b, seg, lane, ts);
}

// Kernel 2: reduce seg/sub-partials + epilogue (softmax class cost + dice).
__global__ __launch_bounds__(64) void finalize_kernel(const float* __restrict__ probs,
                                                      const int*   __restrict__ labels,
                                                      const float* __restrict__ ws,
                                                      float* __restrict__ out) {
    const int bq = blockIdx.x;
    const int b = bq / Q_;

    __shared__ float s_logit[C_];
    for (int c = threadIdx.x; c < C_; c += 64)
        s_logit[c] = probs[(size_t)bq * C_ + c];
    __syncthreads();

    const int t = threadIdx.x;
    if (t < T_) {
        const float4* WL4 = (const float4*)(ws + WL_OFF) + ((size_t)bq * T_ + t) * S_;
        const float4* WI4 = (const float4*)(ws + WI_OFF) + ((size_t)bq * T_ + t) * S_;
        const float4* OS4 = (const float4*)(ws + OS_OFF) + (size_t)bq * S_;
        const float4* GS4 = (const float4*)(ws + GS_OFF) + ((size_t)b * T_ + t) * S_;
        float L = 0.f, I = 0.f, osum = 0.f, tsum = 0.f;
#pragma unroll
        for (int s = 0; s < S_; ++s) {
            const float4 a = WL4[s];
            const float4 v = WI4[s];
            const float4 c = OS4[s];
            const float4 d = GS4[s];
            L    += (a.x + a.y) + (a.z + a.w);
            I    += (v.x + v.y) + (v.z + v.w);
            osum += (c.x + c.y) + (c.z + c.w);
            tsum += (d.x + d.y) + (d.z + d.w);
        }
        float mx = -INFINITY;
#pragma unroll
        for (int c = 0; c < C_; ++c) mx = fmaxf(mx, s_logit[c]);
        float sum = 0.f;
#pragma unroll
        for (int c = 0; c < C_; ++c) sum += __expf(s_logit[c] - mx);
        const int lab = labels[(size_t)b * T_ + t];
        const float p = __expf(s_logit[lab] - mx) / sum;

        const float denom = osum + tsum;
        const float dice = 1.f - (2.f * I + 1.f) / (denom + 1.f);

        out[(size_t)bq * T_ + t] = L - p + dice;
    }
}

extern "C" void kernel_launch(void* const* d_in, const int* in_sizes, int n_in,
                              void* d_out, int out_size, void* d_ws, size_t ws_size,
                              hipStream_t stream) {
    const float* out_probs     = (const float*)d_in[0]; // [B,Q,C]
    const float* out_masks     = (const float*)d_in[1]; // [B,Q,H,W]
    const float* target_masks  = (const float*)d_in[2]; // [B,T,H,W]
    const int*   target_labels = (const int*)d_in[3];   // [B,T]
    float* out = (float*)d_out;                         // [B,Q,T]

    float* partials = (float*)d_ws;                     // ~4.2 MB

    partial_kernel<<<NWG_, 256, 0, stream>>>(out_masks, target_masks, partials);
    finalize_kernel<<<B_ * Q_, 64, 0, stream>>>(out_probs, target_labels, partials, out);
}